// Round 1
// baseline (438.536 us; speedup 1.0000x reference)
//
#include <hip/hip_runtime.h>
#include <math.h>

#define PP 4096
#define CDIM 256
#define NHEADS 4
#define HD 64

__device__ __forceinline__ float wave_sum(float v) {
#pragma unroll
  for (int off = 32; off > 0; off >>= 1) v += __shfl_down(v, off);
  return v;
}

// ---------------- avg pool over H,W ----------------
__global__ __launch_bounds__(256) void k_avg(const float* __restrict__ x,
                                             float* __restrict__ avg) {
  const int bc = blockIdx.x;  // b*256 + c
  const float* src = x + (size_t)bc * PP;
  float s = 0.f;
  for (int i = threadIdx.x; i < PP; i += 256) s += src[i];
  __shared__ float red[4];
  s = wave_sum(s);
  const int lane = threadIdx.x & 63, wid = threadIdx.x >> 6;
  if (lane == 0) red[wid] = s;
  __syncthreads();
  if (threadIdx.x == 0)
    avg[bc] = (red[0] + red[1] + red[2] + red[3]) * (1.0f / PP);
}

// ---------------- dirs + per-(b,h,s,m) normalized offsets ----------------
__global__ void k_dirs(const float* __restrict__ avg, const float* __restrict__ dirW,
                       const float* __restrict__ dirb, float* __restrict__ offs) {
  const int r = threadIdx.x;  // 64 threads: b = r>>5, row = r&31
  __shared__ float dv[2][32];
  {
    const int b = r >> 5, row = r & 31;
    const float* a = avg + b * CDIM;
    const float* w = dirW + row * CDIM;
    float s = dirb[row];
    for (int c = 0; c < CDIM; ++c) s = fmaf(a[c], w[c], s);
    dv[b][row] = s;
  }
  __syncthreads();
  if (r < 32) {  // one (b,h,s) each: b = r>>4, hs = r&15
    const int b = r >> 4, hs = r & 15;
    float vx = dv[b][hs * 2], vy = dv[b][hs * 2 + 1];
    const float n = fmaxf(sqrtf(vx * vx + vy * vy), 1e-6f);
    vx /= n;
    vy /= n;
#pragma unroll
    for (int m = 0; m < 8; ++m) {
      const float t = -0.5f + m * (1.0f / 7.0f);  // linspace(-0.5,0.5,8)
      const int o = ((b * 16 + hs) * 8 + m) * 2;
      offs[o] = vx * t;
      offs[o + 1] = vy * t;
    }
  }
}

// ---------------- SGEMM: out[b][o][p] = sum_c W[o][c] * f(X[b][c][p]) -----
// FINAL=1 fuses GroupNorm affine on input + bias + residual on output.
template <int FINAL>
__global__ __launch_bounds__(256) void k_gemm(
    const float* __restrict__ W, const float* __restrict__ X,
    float* __restrict__ out, const float* __restrict__ stats,
    const float* __restrict__ gnw, const float* __restrict__ gnb,
    const float* __restrict__ bo, const float* __restrict__ resid) {
  const int b = blockIdx.z;
  const int o0 = blockIdx.y * 64;
  const int p0 = blockIdx.x * 64;
  __shared__ float sW[16][64];  // [k][o]
  __shared__ float sX[16][64];  // [k][p]
  const int tr = threadIdx.x >> 4, tc = threadIdx.x & 15;
  float acc[4][4] = {};
  for (int c0 = 0; c0 < CDIM; c0 += 16) {
    {
      const int o = threadIdx.x >> 2, seg = threadIdx.x & 3;
      const float4 w4 = *(const float4*)&W[(o0 + o) * CDIM + c0 + seg * 4];
      sW[seg * 4 + 0][o] = w4.x;
      sW[seg * 4 + 1][o] = w4.y;
      sW[seg * 4 + 2][o] = w4.z;
      sW[seg * 4 + 3][o] = w4.w;
    }
    {
      const int k = threadIdx.x >> 4, sg = threadIdx.x & 15;
      const int c = c0 + k;
      float4 x4 = *(const float4*)&X[((size_t)b * CDIM + c) * PP + p0 + sg * 4];
      if (FINAL) {
        const int g = c >> 6;
        const float mu = stats[(b * NHEADS + g) * 2];
        const float rs = stats[(b * NHEADS + g) * 2 + 1];
        const float A = rs * gnw[c];
        const float Bc = gnb[c] - mu * A;
        x4.x = x4.x * A + Bc;
        x4.y = x4.y * A + Bc;
        x4.z = x4.z * A + Bc;
        x4.w = x4.w * A + Bc;
      }
      *(float4*)&sX[k][sg * 4] = x4;
    }
    __syncthreads();
#pragma unroll
    for (int k = 0; k < 16; ++k) {
      const float4 a = *(const float4*)&sW[k][tr * 4];
      const float4 v = *(const float4*)&sX[k][tc * 4];
      const float av[4] = {a.x, a.y, a.z, a.w};
      const float bv[4] = {v.x, v.y, v.z, v.w};
#pragma unroll
      for (int i = 0; i < 4; ++i)
#pragma unroll
        for (int j = 0; j < 4; ++j) acc[i][j] = fmaf(av[i], bv[j], acc[i][j]);
    }
    __syncthreads();
  }
#pragma unroll
  for (int i = 0; i < 4; ++i) {
    const int o = o0 + tr * 4 + i;
    const size_t base = ((size_t)b * CDIM + o) * PP + p0 + tc * 4;
    float4 r;
    r.x = acc[i][0];
    r.y = acc[i][1];
    r.z = acc[i][2];
    r.w = acc[i][3];
    if (FINAL) {
      const float bb = bo[o];
      const float4 rs = *(const float4*)&resid[base];
      r.x += bb + rs.x;
      r.y += bb + rs.y;
      r.z += bb + rs.z;
      r.w += bb + rs.w;
    }
    *(float4*)&out[base] = r;
  }
}

// ---------------- bilinear sample setup (shift constant per b,h,s,m) ------
struct Samp {
  int i00, i01, i10, i11;
  float w00, w01, w10, w11;
};
__device__ __forceinline__ Samp samp(int xi, int yi, float dxn, float dyn) {
  float gx = fminf(fmaxf(-1.0f + xi * (2.0f / 63.0f) + dxn, -1.0f), 1.0f);
  float gy = fminf(fmaxf(-1.0f + yi * (2.0f / 63.0f) + dyn, -1.0f), 1.0f);
  const float px = (gx + 1.0f) * 31.5f;
  const float py = (gy + 1.0f) * 31.5f;
  const float x0f = floorf(px), y0f = floorf(py);
  const float fx = px - x0f, fy = py - y0f;
  int x0 = (int)x0f;
  x0 = x0 < 0 ? 0 : (x0 > 63 ? 63 : x0);
  int y0 = (int)y0f;
  y0 = y0 < 0 ? 0 : (y0 > 63 ? 63 : y0);
  const int x1 = x0 + 1 > 63 ? 63 : x0 + 1;
  const int y1 = y0 + 1 > 63 ? 63 : y0 + 1;
  Samp sp;
  sp.i00 = y0 * 64 + x0;
  sp.i01 = y0 * 64 + x1;
  sp.i10 = y1 * 64 + x0;
  sp.i11 = y1 * 64 + x1;
  const float ifx = 1.0f - fx, ify = 1.0f - fy;
  sp.w00 = ifx * ify;
  sp.w01 = fx * ify;
  sp.w10 = ifx * fy;
  sp.w11 = fx * fy;
  return sp;
}

// ---------------- logits: one thread per (b,h,p,k) ----------------
__global__ __launch_bounds__(256) void k_logits(const float* __restrict__ Q,
                                                const float* __restrict__ K,
                                                const float* __restrict__ offs,
                                                float* __restrict__ lg) {
  const int p = blockIdx.x * 256 + threadIdx.x;
  const int k = blockIdx.y;   // 0..31  (s = k>>3, m = k&7)
  const int bh = blockIdx.z;  // 0..7
  const int b = bh >> 2, h = bh & 3;
  const int obase = ((b * 16 + h * 4 + (k >> 3)) * 8 + (k & 7)) * 2;
  const Samp sp = samp(p & 63, p >> 6, offs[obase], offs[obase + 1]);
  const float* Qp = Q + ((size_t)b * CDIM + h * HD) * PP + p;
  const float* Kp = K + ((size_t)b * CDIM + h * HD) * PP;
  float acc = 0.f;
#pragma unroll 8
  for (int d = 0; d < HD; ++d) {
    const float* Kd = Kp + (size_t)d * PP;
    const float bil = sp.w00 * Kd[sp.i00] + sp.w01 * Kd[sp.i01] +
                      sp.w10 * Kd[sp.i10] + sp.w11 * Kd[sp.i11];
    acc = fmaf(Qp[(size_t)d * PP], bil, acc);
  }
  lg[((size_t)bh * 32 + k) * PP + p] = acc * 0.125f;  // SCALE = hd^-0.5
}

// ---------------- softmax over k=32, in place ----------------
__global__ __launch_bounds__(256) void k_softmax(float* __restrict__ lg) {
  const int idx = blockIdx.x * 256 + threadIdx.x;  // 0..32767
  const int bh = idx >> 12, p = idx & 4095;
  float* base = lg + (size_t)bh * 32 * PP + p;
  float v[32];
  float mx = -1e30f;
#pragma unroll
  for (int k = 0; k < 32; ++k) {
    v[k] = base[(size_t)k * PP];
    mx = fmaxf(mx, v[k]);
  }
  float sum = 0.f;
#pragma unroll
  for (int k = 0; k < 32; ++k) {
    v[k] = __expf(v[k] - mx);
    sum += v[k];
  }
  const float inv = 1.0f / sum;
#pragma unroll
  for (int k = 0; k < 32; ++k) base[(size_t)k * PP] = v[k] * inv;
}

// ---------------- PV: one thread per (b,h,p, 8-d group) ----------------
__global__ __launch_bounds__(256) void k_pv(const float* __restrict__ V,
                                            const float* __restrict__ aw,
                                            const float* __restrict__ offs,
                                            float* __restrict__ O) {
  const int p = blockIdx.x * 256 + threadIdx.x;
  const int dg = blockIdx.y;  // 0..7
  const int bh = blockIdx.z;  // 0..7
  const int b = bh >> 2, h = bh & 3;
  const float* Vp = V + ((size_t)b * CDIM + h * HD + dg * 8) * PP;
  const float* ap = aw + (size_t)bh * 32 * PP + p;
  float o[8] = {};
  for (int k = 0; k < 32; ++k) {
    const int obase = ((b * 16 + h * 4 + (k >> 3)) * 8 + (k & 7)) * 2;
    const Samp sp = samp(p & 63, p >> 6, offs[obase], offs[obase + 1]);
    const float w = ap[(size_t)k * PP];
    const float a00 = w * sp.w00, a01 = w * sp.w01;
    const float a10 = w * sp.w10, a11 = w * sp.w11;
#pragma unroll
    for (int d = 0; d < 8; ++d) {
      const float* Vd = Vp + (size_t)d * PP;
      o[d] += a00 * Vd[sp.i00] + a01 * Vd[sp.i01] + a10 * Vd[sp.i10] +
              a11 * Vd[sp.i11];
    }
  }
#pragma unroll
  for (int d = 0; d < 8; ++d)
    O[((size_t)b * CDIM + h * HD + dg * 8 + d) * PP + p] = o[d];
}

// ---------------- GroupNorm stats per (b, head-group) ----------------
__global__ __launch_bounds__(256) void k_gnstats(const float* __restrict__ O,
                                                 float* __restrict__ stats) {
  const int bh = blockIdx.x;  // 0..7 ; group channels are contiguous in [b][c][p]
  const float* src = O + (size_t)bh * (HD * PP);
  float s1 = 0.f, s2 = 0.f;
  for (int i = threadIdx.x; i < HD * PP; i += 256) {
    const float v = src[i];
    s1 += v;
    s2 += v * v;
  }
  __shared__ float r1[4], r2[4];
  s1 = wave_sum(s1);
  s2 = wave_sum(s2);
  const int lane = threadIdx.x & 63, wid = threadIdx.x >> 6;
  if (lane == 0) {
    r1[wid] = s1;
    r2[wid] = s2;
  }
  __syncthreads();
  if (threadIdx.x == 0) {
    const float S1 = r1[0] + r1[1] + r1[2] + r1[3];
    const float S2 = r2[0] + r2[1] + r2[2] + r2[3];
    const float inv = 1.0f / (HD * PP);
    const float mu = S1 * inv;
    const float var = S2 * inv - mu * mu;
    stats[bh * 2] = mu;
    stats[bh * 2 + 1] = rsqrtf(var + 1e-5f);
  }
}

extern "C" void kernel_launch(void* const* d_in, const int* in_sizes, int n_in,
                              void* d_out, int out_size, void* d_ws,
                              size_t ws_size, hipStream_t stream) {
  const float* x = (const float*)d_in[0];
  const float* Wq = (const float*)d_in[1];
  const float* Wk = (const float*)d_in[2];
  const float* Wv = (const float*)d_in[3];
  const float* Wo = (const float*)d_in[4];
  const float* bo = (const float*)d_in[5];
  const float* dirW = (const float*)d_in[6];
  const float* dirb = (const float*)d_in[7];
  const float* gnw = (const float*)d_in[8];
  const float* gnb = (const float*)d_in[9];
  float* outp = (float*)d_out;

  float* ws = (float*)d_ws;
  float* avg = ws;                    // 512
  float* offs = ws + 512;             // 1024
  float* Qb = ws + 2048;              // 2,097,152  [b][c][p]
  float* Kb = Qb + 2097152;           // 2,097,152
  float* Vb = Kb + 2097152;           // 2,097,152
  float* lg = Vb + 2097152;           // 1,048,576  [bh][k][p] (softmax in place)
  float* Ob = lg + 1048576;           // 2,097,152  [b][c][p]
  float* stats = Ob + 2097152;        // 16

  k_avg<<<dim3(512), dim3(256), 0, stream>>>(x, avg);
  k_dirs<<<dim3(1), dim3(64), 0, stream>>>(avg, dirW, dirb, offs);
  k_gemm<0><<<dim3(64, 4, 2), dim3(256), 0, stream>>>(
      Wq, x, Qb, nullptr, nullptr, nullptr, nullptr, nullptr);
  k_gemm<0><<<dim3(64, 4, 2), dim3(256), 0, stream>>>(
      Wk, x, Kb, nullptr, nullptr, nullptr, nullptr, nullptr);
  k_gemm<0><<<dim3(64, 4, 2), dim3(256), 0, stream>>>(
      Wv, x, Vb, nullptr, nullptr, nullptr, nullptr, nullptr);
  k_logits<<<dim3(16, 32, 8), dim3(256), 0, stream>>>(Qb, Kb, offs, lg);
  k_softmax<<<dim3(128), dim3(256), 0, stream>>>(lg);
  k_pv<<<dim3(16, 8, 8), dim3(256), 0, stream>>>(Vb, lg, offs, Ob);
  k_gnstats<<<dim3(8), dim3(256), 0, stream>>>(Ob, stats);
  k_gemm<1><<<dim3(64, 4, 2), dim3(256), 0, stream>>>(Wo, Ob, outp, stats, gnw,
                                                      gnb, bo, x);
}

// Round 2
// 175.518 us; speedup vs baseline: 2.4985x; 2.4985x over previous
//
#include <hip/hip_runtime.h>
#include <math.h>

#define PP 4096
#define CDIM 256
#define NHEADS 4
#define HD 64

__device__ __forceinline__ float wave_sum(float v) {
#pragma unroll
  for (int off = 32; off > 0; off >>= 1) v += __shfl_down(v, off);
  return v;
}

// ---------------- avg pool over H,W ----------------
__global__ __launch_bounds__(256) void k_avg(const float* __restrict__ x,
                                             float* __restrict__ avg) {
  const int bc = blockIdx.x;  // b*256 + c
  const float* src = x + (size_t)bc * PP;
  float s = 0.f;
  for (int i = threadIdx.x; i < PP; i += 256) s += src[i];
  __shared__ float red[4];
  s = wave_sum(s);
  const int lane = threadIdx.x & 63, wid = threadIdx.x >> 6;
  if (lane == 0) red[wid] = s;
  __syncthreads();
  if (threadIdx.x == 0)
    avg[bc] = (red[0] + red[1] + red[2] + red[3]) * (1.0f / PP);
}

// ---------------- dirs + per-(b,h,s,m) normalized offsets ----------------
__global__ void k_dirs(const float* __restrict__ avg, const float* __restrict__ dirW,
                       const float* __restrict__ dirb, float* __restrict__ offs) {
  const int r = threadIdx.x;  // 64 threads: b = r>>5, row = r&31
  __shared__ float dv[2][32];
  {
    const int b = r >> 5, row = r & 31;
    const float* a = avg + b * CDIM;
    const float* w = dirW + row * CDIM;
    float s = dirb[row];
    for (int c = 0; c < CDIM; ++c) s = fmaf(a[c], w[c], s);
    dv[b][row] = s;
  }
  __syncthreads();
  if (r < 32) {  // one (b,h,s) each: b = r>>4, hs = r&15
    const int b = r >> 4, hs = r & 15;
    float vx = dv[b][hs * 2], vy = dv[b][hs * 2 + 1];
    const float n = fmaxf(sqrtf(vx * vx + vy * vy), 1e-6f);
    vx /= n;
    vy /= n;
#pragma unroll
    for (int m = 0; m < 8; ++m) {
      const float t = -0.5f + m * (1.0f / 7.0f);  // linspace(-0.5,0.5,8)
      const int o = ((b * 16 + hs) * 8 + m) * 2;
      offs[o] = vx * t;
      offs[o + 1] = vy * t;
    }
  }
}

// ---------------- SGEMM: out[b][o][p] = sum_c W[o][c] * f(X[b][c][p]) -----
// FINAL=1 fuses GroupNorm affine on input + bias + residual on output.
template <int FINAL>
__global__ __launch_bounds__(256) void k_gemm(
    const float* __restrict__ W, const float* __restrict__ X,
    float* __restrict__ out, const float* __restrict__ stats,
    const float* __restrict__ gnw, const float* __restrict__ gnb,
    const float* __restrict__ bo, const float* __restrict__ resid) {
  const int b = blockIdx.z;
  const int o0 = blockIdx.y * 64;
  const int p0 = blockIdx.x * 64;
  __shared__ float sW[16][64];  // [k][o]
  __shared__ float sX[16][64];  // [k][p]
  const int tr = threadIdx.x >> 4, tc = threadIdx.x & 15;
  float acc[4][4] = {};
  for (int c0 = 0; c0 < CDIM; c0 += 16) {
    {
      const int o = threadIdx.x >> 2, seg = threadIdx.x & 3;
      const float4 w4 = *(const float4*)&W[(o0 + o) * CDIM + c0 + seg * 4];
      sW[seg * 4 + 0][o] = w4.x;
      sW[seg * 4 + 1][o] = w4.y;
      sW[seg * 4 + 2][o] = w4.z;
      sW[seg * 4 + 3][o] = w4.w;
    }
    {
      const int k = threadIdx.x >> 4, sg = threadIdx.x & 15;
      const int c = c0 + k;
      float4 x4 = *(const float4*)&X[((size_t)b * CDIM + c) * PP + p0 + sg * 4];
      if (FINAL) {
        const int g = c >> 6;
        const float mu = stats[(b * NHEADS + g) * 2];
        const float rs = stats[(b * NHEADS + g) * 2 + 1];
        const float A = rs * gnw[c];
        const float Bc = gnb[c] - mu * A;
        x4.x = x4.x * A + Bc;
        x4.y = x4.y * A + Bc;
        x4.z = x4.z * A + Bc;
        x4.w = x4.w * A + Bc;
      }
      *(float4*)&sX[k][sg * 4] = x4;
    }
    __syncthreads();
#pragma unroll
    for (int k = 0; k < 16; ++k) {
      const float4 a = *(const float4*)&sW[k][tr * 4];
      const float4 v = *(const float4*)&sX[k][tc * 4];
      const float av[4] = {a.x, a.y, a.z, a.w};
      const float bv[4] = {v.x, v.y, v.z, v.w};
#pragma unroll
      for (int i = 0; i < 4; ++i)
#pragma unroll
        for (int j = 0; j < 4; ++j) acc[i][j] = fmaf(av[i], bv[j], acc[i][j]);
    }
    __syncthreads();
  }
#pragma unroll
  for (int i = 0; i < 4; ++i) {
    const int o = o0 + tr * 4 + i;
    const size_t base = ((size_t)b * CDIM + o) * PP + p0 + tc * 4;
    float4 r;
    r.x = acc[i][0];
    r.y = acc[i][1];
    r.z = acc[i][2];
    r.w = acc[i][3];
    if (FINAL) {
      const float bb = bo[o];
      const float4 rs = *(const float4*)&resid[base];
      r.x += bb + rs.x;
      r.y += bb + rs.y;
      r.z += bb + rs.z;
      r.w += bb + rs.w;
    }
    *(float4*)&out[base] = r;
  }
}

// ---------------- bilinear sample setup (shift constant per b,h,s,m) ------
struct Samp {
  int i00, i01, i10, i11;
  float w00, w01, w10, w11;
};
__device__ __forceinline__ Samp samp(int xi, int yi, float dxn, float dyn) {
  float gx = fminf(fmaxf(-1.0f + xi * (2.0f / 63.0f) + dxn, -1.0f), 1.0f);
  float gy = fminf(fmaxf(-1.0f + yi * (2.0f / 63.0f) + dyn, -1.0f), 1.0f);
  const float px = (gx + 1.0f) * 31.5f;
  const float py = (gy + 1.0f) * 31.5f;
  const float x0f = floorf(px), y0f = floorf(py);
  const float fx = px - x0f, fy = py - y0f;
  int x0 = (int)x0f;
  x0 = x0 < 0 ? 0 : (x0 > 63 ? 63 : x0);
  int y0 = (int)y0f;
  y0 = y0 < 0 ? 0 : (y0 > 63 ? 63 : y0);
  const int x1 = x0 + 1 > 63 ? 63 : x0 + 1;
  const int y1 = y0 + 1 > 63 ? 63 : y0 + 1;
  Samp sp;
  sp.i00 = y0 * 64 + x0;
  sp.i01 = y0 * 64 + x1;
  sp.i10 = y1 * 64 + x0;
  sp.i11 = y1 * 64 + x1;
  const float ifx = 1.0f - fx, ify = 1.0f - fy;
  sp.w00 = ifx * ify;
  sp.w01 = fx * ify;
  sp.w10 = ifx * fy;
  sp.w11 = fx * fy;
  return sp;
}

// ---------------- logits: one thread per (b,h,p,k) ----------------
__global__ __launch_bounds__(256) void k_logits(const float* __restrict__ Q,
                                                const float* __restrict__ K,
                                                const float* __restrict__ offs,
                                                float* __restrict__ lg) {
  const int p = blockIdx.x * 256 + threadIdx.x;
  const int k = blockIdx.y;   // 0..31  (s = k>>3, m = k&7)
  const int bh = blockIdx.z;  // 0..7
  const int b = bh >> 2, h = bh & 3;
  const int obase = ((b * 16 + h * 4 + (k >> 3)) * 8 + (k & 7)) * 2;
  const Samp sp = samp(p & 63, p >> 6, offs[obase], offs[obase + 1]);
  const float* Qp = Q + ((size_t)b * CDIM + h * HD) * PP + p;
  const float* Kp = K + ((size_t)b * CDIM + h * HD) * PP;
  float acc = 0.f;
#pragma unroll 8
  for (int d = 0; d < HD; ++d) {
    const float* Kd = Kp + (size_t)d * PP;
    const float bil = sp.w00 * Kd[sp.i00] + sp.w01 * Kd[sp.i01] +
                      sp.w10 * Kd[sp.i10] + sp.w11 * Kd[sp.i11];
    acc = fmaf(Qp[(size_t)d * PP], bil, acc);
  }
  lg[((size_t)bh * 32 + k) * PP + p] = acc * 0.125f;  // SCALE = hd^-0.5
}

// ---------------- softmax over k=32, in place ----------------
__global__ __launch_bounds__(256) void k_softmax(float* __restrict__ lg) {
  const int idx = blockIdx.x * 256 + threadIdx.x;  // 0..32767
  const int bh = idx >> 12, p = idx & 4095;
  float* base = lg + (size_t)bh * 32 * PP + p;
  float v[32];
  float mx = -1e30f;
#pragma unroll
  for (int k = 0; k < 32; ++k) {
    v[k] = base[(size_t)k * PP];
    mx = fmaxf(mx, v[k]);
  }
  float sum = 0.f;
#pragma unroll
  for (int k = 0; k < 32; ++k) {
    v[k] = __expf(v[k] - mx);
    sum += v[k];
  }
  const float inv = 1.0f / sum;
#pragma unroll
  for (int k = 0; k < 32; ++k) base[(size_t)k * PP] = v[k] * inv;
}

// ---------------- PV: one thread per (b,h,p, 8-d group) ----------------
__global__ __launch_bounds__(256) void k_pv(const float* __restrict__ V,
                                            const float* __restrict__ aw,
                                            const float* __restrict__ offs,
                                            float* __restrict__ O) {
  const int p = blockIdx.x * 256 + threadIdx.x;
  const int dg = blockIdx.y;  // 0..7
  const int bh = blockIdx.z;  // 0..7
  const int b = bh >> 2, h = bh & 3;
  const float* Vp = V + ((size_t)b * CDIM + h * HD + dg * 8) * PP;
  const float* ap = aw + (size_t)bh * 32 * PP + p;
  float o[8] = {};
  for (int k = 0; k < 32; ++k) {
    const int obase = ((b * 16 + h * 4 + (k >> 3)) * 8 + (k & 7)) * 2;
    const Samp sp = samp(p & 63, p >> 6, offs[obase], offs[obase + 1]);
    const float w = ap[(size_t)k * PP];
    const float a00 = w * sp.w00, a01 = w * sp.w01;
    const float a10 = w * sp.w10, a11 = w * sp.w11;
#pragma unroll
    for (int d = 0; d < 8; ++d) {
      const float* Vd = Vp + (size_t)d * PP;
      o[d] += a00 * Vd[sp.i00] + a01 * Vd[sp.i01] + a10 * Vd[sp.i10] +
              a11 * Vd[sp.i11];
    }
  }
#pragma unroll
  for (int d = 0; d < 8; ++d)
    O[((size_t)b * CDIM + h * HD + dg * 8 + d) * PP + p] = o[d];
}

// ---------------- GroupNorm stats, two-stage ----------------
// stage 1: 8 groups x 32 chunks; each block reduces 8192 elems -> partial
__global__ __launch_bounds__(256) void k_gnstats1(const float* __restrict__ O,
                                                  float* __restrict__ part) {
  const int bh = blockIdx.x >> 5;    // 0..7
  const int chunk = blockIdx.x & 31; // 0..31
  const float* src = O + (size_t)bh * (HD * PP) + (size_t)chunk * 8192;
  float s1 = 0.f, s2 = 0.f;
  for (int i = threadIdx.x * 4; i < 8192; i += 1024) {
    const float4 v4 = *(const float4*)&src[i];
    s1 += v4.x + v4.y + v4.z + v4.w;
    s2 += v4.x * v4.x + v4.y * v4.y + v4.z * v4.z + v4.w * v4.w;
  }
  __shared__ float r1[4], r2[4];
  s1 = wave_sum(s1);
  s2 = wave_sum(s2);
  const int lane = threadIdx.x & 63, wid = threadIdx.x >> 6;
  if (lane == 0) {
    r1[wid] = s1;
    r2[wid] = s2;
  }
  __syncthreads();
  if (threadIdx.x == 0) {
    part[blockIdx.x * 2] = r1[0] + r1[1] + r1[2] + r1[3];
    part[blockIdx.x * 2 + 1] = r2[0] + r2[1] + r2[2] + r2[3];
  }
}

// stage 2: one block, 8 waves would be overkill; 64 threads -> 8 groups
__global__ void k_gnstats2(const float* __restrict__ part,
                           float* __restrict__ stats) {
  const int t = threadIdx.x;  // 0..63 ; group = t>>3, sub = t&7
  const int g = t >> 3, sub = t & 7;
  float s1 = 0.f, s2 = 0.f;
  for (int c = sub * 4; c < (sub + 1) * 4; ++c) {
    s1 += part[(g * 32 + c) * 2];
    s2 += part[(g * 32 + c) * 2 + 1];
  }
#pragma unroll
  for (int off = 4; off > 0; off >>= 1) {
    s1 += __shfl_down(s1, off);
    s2 += __shfl_down(s2, off);
  }
  if (sub == 0) {
    const float inv = 1.0f / (HD * PP);
    const float mu = s1 * inv;
    const float var = s2 * inv - mu * mu;
    stats[g * 2] = mu;
    stats[g * 2 + 1] = rsqrtf(var + 1e-5f);
  }
}

extern "C" void kernel_launch(void* const* d_in, const int* in_sizes, int n_in,
                              void* d_out, int out_size, void* d_ws,
                              size_t ws_size, hipStream_t stream) {
  const float* x = (const float*)d_in[0];
  const float* Wq = (const float*)d_in[1];
  const float* Wk = (const float*)d_in[2];
  const float* Wv = (const float*)d_in[3];
  const float* Wo = (const float*)d_in[4];
  const float* bo = (const float*)d_in[5];
  const float* dirW = (const float*)d_in[6];
  const float* dirb = (const float*)d_in[7];
  const float* gnw = (const float*)d_in[8];
  const float* gnb = (const float*)d_in[9];
  float* outp = (float*)d_out;

  float* ws = (float*)d_ws;
  float* avg = ws;                    // 512
  float* offs = ws + 512;             // 1024
  float* stats = ws + 1536;           // 16
  float* part = ws + 1600;            // 512
  float* Qb = ws + 4096;              // 2,097,152  [b][c][p]
  float* Kb = Qb + 2097152;           // 2,097,152
  float* Vb = Kb + 2097152;           // 2,097,152
  float* lg = Vb + 2097152;           // 1,048,576  [bh][k][p] (softmax in place)
  float* Ob = lg + 1048576;           // 2,097,152  [b][c][p]

  k_avg<<<dim3(512), dim3(256), 0, stream>>>(x, avg);
  k_dirs<<<dim3(1), dim3(64), 0, stream>>>(avg, dirW, dirb, offs);
  k_gemm<0><<<dim3(64, 4, 2), dim3(256), 0, stream>>>(
      Wq, x, Qb, nullptr, nullptr, nullptr, nullptr, nullptr);
  k_gemm<0><<<dim3(64, 4, 2), dim3(256), 0, stream>>>(
      Wk, x, Kb, nullptr, nullptr, nullptr, nullptr, nullptr);
  k_gemm<0><<<dim3(64, 4, 2), dim3(256), 0, stream>>>(
      Wv, x, Vb, nullptr, nullptr, nullptr, nullptr, nullptr);
  k_logits<<<dim3(16, 32, 8), dim3(256), 0, stream>>>(Qb, Kb, offs, lg);
  k_softmax<<<dim3(128), dim3(256), 0, stream>>>(lg);
  k_pv<<<dim3(16, 8, 8), dim3(256), 0, stream>>>(Vb, lg, offs, Ob);
  k_gnstats1<<<dim3(256), dim3(256), 0, stream>>>(Ob, part);
  k_gnstats2<<<dim3(1), dim3(64), 0, stream>>>(part, stats);
  k_gemm<1><<<dim3(64, 4, 2), dim3(256), 0, stream>>>(Wo, Ob, outp, stats, gnw,
                                                      gnb, bo, x);
}

// Round 3
// 152.809 us; speedup vs baseline: 2.8698x; 1.1486x over previous
//
#include <hip/hip_runtime.h>
#include <math.h>

#define PP 4096
#define CDIM 256
#define NHEADS 4
#define HD 64

typedef unsigned int u32t;
typedef unsigned short u16t;

__device__ __forceinline__ float wave_sum(float v) {
#pragma unroll
  for (int off = 32; off > 0; off >>= 1) v += __shfl_down(v, off);
  return v;
}

__device__ __forceinline__ float bflo(u32t w) {
  return __uint_as_float(w << 16);
}
__device__ __forceinline__ float bfhi(u32t w) {
  return __uint_as_float(w & 0xffff0000u);
}

// ---------------- avg pool over H,W ----------------
__global__ __launch_bounds__(256) void k_avg(const float* __restrict__ x,
                                             float* __restrict__ avg) {
  const int bc = blockIdx.x;  // b*256 + c
  const float* src = x + (size_t)bc * PP;
  float s = 0.f;
  for (int i = threadIdx.x; i < PP; i += 256) s += src[i];
  __shared__ float red[4];
  s = wave_sum(s);
  const int lane = threadIdx.x & 63, wid = threadIdx.x >> 6;
  if (lane == 0) red[wid] = s;
  __syncthreads();
  if (threadIdx.x == 0)
    avg[bc] = (red[0] + red[1] + red[2] + red[3]) * (1.0f / PP);
}

// ---------------- dirs + per-(b,h,s,m) normalized offsets ----------------
__global__ void k_dirs(const float* __restrict__ avg, const float* __restrict__ dirW,
                       const float* __restrict__ dirb, float* __restrict__ offs) {
  const int r = threadIdx.x;  // 64 threads: b = r>>5, row = r&31
  __shared__ float dv[2][32];
  {
    const int b = r >> 5, row = r & 31;
    const float* a = avg + b * CDIM;
    const float* w = dirW + row * CDIM;
    float s = dirb[row];
    for (int c = 0; c < CDIM; ++c) s = fmaf(a[c], w[c], s);
    dv[b][row] = s;
  }
  __syncthreads();
  if (r < 32) {  // one (b,h,s) each: b = r>>4, hs = r&15
    const int b = r >> 4, hs = r & 15;
    float vx = dv[b][hs * 2], vy = dv[b][hs * 2 + 1];
    const float n = fmaxf(sqrtf(vx * vx + vy * vy), 1e-6f);
    vx /= n;
    vy /= n;
#pragma unroll
    for (int m = 0; m < 8; ++m) {
      const float t = -0.5f + m * (1.0f / 7.0f);  // linspace(-0.5,0.5,8)
      const int o = ((b * 16 + hs) * 8 + m) * 2;
      offs[o] = vx * t;
      offs[o + 1] = vy * t;
    }
  }
}

// ---------------- SGEMM: out[b][o][p] = sum_c W[o][c] * f(X[b][c][p]) -----
// FINAL=1 fuses GroupNorm affine on input + bias + residual on output.
template <int FINAL>
__global__ __launch_bounds__(256) void k_gemm(
    const float* __restrict__ W, const float* __restrict__ X,
    float* __restrict__ out, const float* __restrict__ stats,
    const float* __restrict__ gnw, const float* __restrict__ gnb,
    const float* __restrict__ bo, const float* __restrict__ resid) {
  const int b = blockIdx.z;
  const int o0 = blockIdx.y * 64;
  const int p0 = blockIdx.x * 64;
  __shared__ float sW[16][64];  // [k][o]
  __shared__ float sX[16][64];  // [k][p]
  const int tr = threadIdx.x >> 4, tc = threadIdx.x & 15;
  float acc[4][4] = {};
  for (int c0 = 0; c0 < CDIM; c0 += 16) {
    {
      const int o = threadIdx.x >> 2, seg = threadIdx.x & 3;
      const float4 w4 = *(const float4*)&W[(o0 + o) * CDIM + c0 + seg * 4];
      sW[seg * 4 + 0][o] = w4.x;
      sW[seg * 4 + 1][o] = w4.y;
      sW[seg * 4 + 2][o] = w4.z;
      sW[seg * 4 + 3][o] = w4.w;
    }
    {
      const int k = threadIdx.x >> 4, sg = threadIdx.x & 15;
      const int c = c0 + k;
      float4 x4 = *(const float4*)&X[((size_t)b * CDIM + c) * PP + p0 + sg * 4];
      if (FINAL) {
        const int g = c >> 6;
        const float mu = stats[(b * NHEADS + g) * 2];
        const float rs = stats[(b * NHEADS + g) * 2 + 1];
        const float A = rs * gnw[c];
        const float Bc = gnb[c] - mu * A;
        x4.x = x4.x * A + Bc;
        x4.y = x4.y * A + Bc;
        x4.z = x4.z * A + Bc;
        x4.w = x4.w * A + Bc;
      }
      *(float4*)&sX[k][sg * 4] = x4;
    }
    __syncthreads();
#pragma unroll
    for (int k = 0; k < 16; ++k) {
      const float4 a = *(const float4*)&sW[k][tr * 4];
      const float4 v = *(const float4*)&sX[k][tc * 4];
      const float av[4] = {a.x, a.y, a.z, a.w};
      const float bv[4] = {v.x, v.y, v.z, v.w};
#pragma unroll
      for (int i = 0; i < 4; ++i)
#pragma unroll
        for (int j = 0; j < 4; ++j) acc[i][j] = fmaf(av[i], bv[j], acc[i][j]);
    }
    __syncthreads();
  }
#pragma unroll
  for (int i = 0; i < 4; ++i) {
    const int o = o0 + tr * 4 + i;
    const size_t base = ((size_t)b * CDIM + o) * PP + p0 + tc * 4;
    float4 r;
    r.x = acc[i][0];
    r.y = acc[i][1];
    r.z = acc[i][2];
    r.w = acc[i][3];
    if (FINAL) {
      const float bb = bo[o];
      const float4 rs = *(const float4*)&resid[base];
      r.x += bb + rs.x;
      r.y += bb + rs.y;
      r.z += bb + rs.z;
      r.w += bb + rs.w;
    }
    *(float4*)&out[base] = r;
  }
}

// ---------------- repack f32 [b][c][p] -> bf16 chunked [bh][c8][p][8] -----
__global__ __launch_bounds__(256) void k_repack(const float* __restrict__ src,
                                                u16t* __restrict__ dst) {
  const int p = blockIdx.x * 256 + threadIdx.x;
  const int c8 = blockIdx.y;  // 0..7
  const int bh = blockIdx.z;  // 0..7
  const int b = bh >> 2, h = bh & 3;
  const float* s = src + ((size_t)b * CDIM + h * HD + c8 * 8) * PP + p;
  u32t u[4];
#pragma unroll
  for (int jw = 0; jw < 4; ++jw) {
    const u32t blo = __float_as_uint(s[(size_t)(2 * jw) * PP]);
    const u32t bhi = __float_as_uint(s[(size_t)(2 * jw + 1) * PP]);
    const u32t lo = (blo + 0x7fffu + ((blo >> 16) & 1u)) >> 16;
    const u32t hi = (bhi + 0x7fffu + ((bhi >> 16) & 1u)) & 0xffff0000u;
    u[jw] = lo | hi;
  }
  *(uint4*)&dst[(((size_t)bh * 8 + c8) * PP + p) * 8] = *(const uint4*)u;
}

// ---------------- bilinear sample setup (shift constant per b,h,s,m) ------
struct Samp {
  int i00, i01, i10, i11;
  float w00, w01, w10, w11;
};
__device__ __forceinline__ Samp samp(int xi, int yi, float dxn, float dyn) {
  float gx = fminf(fmaxf(-1.0f + xi * (2.0f / 63.0f) + dxn, -1.0f), 1.0f);
  float gy = fminf(fmaxf(-1.0f + yi * (2.0f / 63.0f) + dyn, -1.0f), 1.0f);
  const float px = (gx + 1.0f) * 31.5f;
  const float py = (gy + 1.0f) * 31.5f;
  const float x0f = floorf(px), y0f = floorf(py);
  const float fx = px - x0f, fy = py - y0f;
  int x0 = (int)x0f;
  x0 = x0 < 0 ? 0 : (x0 > 63 ? 63 : x0);
  int y0 = (int)y0f;
  y0 = y0 < 0 ? 0 : (y0 > 63 ? 63 : y0);
  const int x1 = x0 + 1 > 63 ? 63 : x0 + 1;
  const int y1 = y0 + 1 > 63 ? 63 : y0 + 1;
  Samp sp;
  sp.i00 = y0 * 64 + x0;
  sp.i01 = y0 * 64 + x1;
  sp.i10 = y1 * 64 + x0;
  sp.i11 = y1 * 64 + x1;
  const float ifx = 1.0f - fx, ify = 1.0f - fy;
  sp.w00 = ifx * ify;
  sp.w01 = fx * ify;
  sp.w10 = ifx * fy;
  sp.w11 = fx * fy;
  return sp;
}

__device__ __forceinline__ float dot8(const float* q, uint4 v) {
  float a = q[0] * bflo(v.x);
  a = fmaf(q[1], bfhi(v.x), a);
  a = fmaf(q[2], bflo(v.y), a);
  a = fmaf(q[3], bfhi(v.y), a);
  a = fmaf(q[4], bflo(v.z), a);
  a = fmaf(q[5], bfhi(v.z), a);
  a = fmaf(q[6], bflo(v.w), a);
  a = fmaf(q[7], bfhi(v.w), a);
  return a;
}

// ---------------- logits: thread per (p, strip) over 8 m ----------------
__global__ __launch_bounds__(256) void k_logits(const float* __restrict__ Q,
                                                const uint4* __restrict__ Kc,
                                                const float* __restrict__ offs,
                                                float* __restrict__ lg) {
  const int p = blockIdx.x * 256 + threadIdx.x;
  const int s = blockIdx.y;   // strip 0..3
  const int bh = blockIdx.z;  // 0..7
  const int b = bh >> 2, h = bh & 3;
  float q[64];
  {
    const float* Qp = Q + ((size_t)b * CDIM + h * HD) * PP + p;
#pragma unroll
    for (int d = 0; d < 64; ++d) q[d] = Qp[(size_t)d * PP];
  }
  const int xi = p & 63, yi = p >> 6;
  for (int m = 0; m < 8; ++m) {
    const int obase = ((b * 16 + h * 4 + s) * 8 + m) * 2;
    const Samp sp = samp(xi, yi, offs[obase], offs[obase + 1]);
    float a00 = 0.f, a01 = 0.f, a10 = 0.f, a11 = 0.f;
#pragma unroll
    for (int c8 = 0; c8 < 8; ++c8) {
      const uint4* Kb8 = Kc + ((size_t)bh * 8 + c8) * PP;
      const uint4 v00 = Kb8[sp.i00];
      const uint4 v01 = Kb8[sp.i01];
      const uint4 v10 = Kb8[sp.i10];
      const uint4 v11 = Kb8[sp.i11];
      const float* qq = q + c8 * 8;
      a00 += dot8(qq, v00);
      a01 += dot8(qq, v01);
      a10 += dot8(qq, v10);
      a11 += dot8(qq, v11);
    }
    const float lgv =
        (sp.w00 * a00 + sp.w01 * a01 + sp.w10 * a10 + sp.w11 * a11) * 0.125f;
    lg[((size_t)bh * 32 + s * 8 + m) * PP + p] = lgv;
  }
}

__device__ __forceinline__ void acc8(float* a, uint4 v, float w) {
  a[0] = fmaf(w, bflo(v.x), a[0]);
  a[1] = fmaf(w, bfhi(v.x), a[1]);
  a[2] = fmaf(w, bflo(v.y), a[2]);
  a[3] = fmaf(w, bfhi(v.y), a[3]);
  a[4] = fmaf(w, bflo(v.z), a[4]);
  a[5] = fmaf(w, bfhi(v.z), a[5]);
  a[6] = fmaf(w, bflo(v.w), a[6]);
  a[7] = fmaf(w, bfhi(v.w), a[7]);
}

// ---------------- PV with fused softmax: thread per (p, 16-d group) -------
__global__ __launch_bounds__(256) void k_pv(const uint4* __restrict__ Vc,
                                            const float* __restrict__ lg,
                                            const float* __restrict__ offs,
                                            float* __restrict__ O) {
  const int p = blockIdx.x * 256 + threadIdx.x;
  const int g = blockIdx.y;   // 0..3 -> d range g*16..g*16+15
  const int bh = blockIdx.z;  // 0..7
  const int b = bh >> 2, h = bh & 3;
  const float* ap = lg + (size_t)bh * 32 * PP + p;
  // softmax pass 1: max
  float mx = -1e30f;
#pragma unroll
  for (int k = 0; k < 32; ++k) mx = fmaxf(mx, ap[(size_t)k * PP]);
  // softmax pass 2: denom
  float sum = 0.f;
#pragma unroll
  for (int k = 0; k < 32; ++k) sum += __expf(ap[(size_t)k * PP] - mx);
  const float inv = 1.0f / sum;
  const int xi = p & 63, yi = p >> 6;
  float acc[16] = {};
  for (int k = 0; k < 32; ++k) {
    const int obase = ((b * 16 + h * 4 + (k >> 3)) * 8 + (k & 7)) * 2;
    const Samp sp = samp(xi, yi, offs[obase], offs[obase + 1]);
    const float ww = __expf(ap[(size_t)k * PP] - mx) * inv;
    const float w00 = ww * sp.w00, w01 = ww * sp.w01;
    const float w10 = ww * sp.w10, w11 = ww * sp.w11;
#pragma unroll
    for (int cc = 0; cc < 2; ++cc) {
      const uint4* Vb8 = Vc + ((size_t)bh * 8 + 2 * g + cc) * PP;
      const uint4 v00 = Vb8[sp.i00];
      const uint4 v01 = Vb8[sp.i01];
      const uint4 v10 = Vb8[sp.i10];
      const uint4 v11 = Vb8[sp.i11];
      float* a = acc + cc * 8;
      acc8(a, v00, w00);
      acc8(a, v01, w01);
      acc8(a, v10, w10);
      acc8(a, v11, w11);
    }
  }
  const size_t ob = ((size_t)b * CDIM + h * HD + g * 16) * PP + p;
#pragma unroll
  for (int d = 0; d < 16; ++d) O[ob + (size_t)d * PP] = acc[d];
}

// ---------------- GroupNorm stats, two-stage ----------------
__global__ __launch_bounds__(256) void k_gnstats1(const float* __restrict__ O,
                                                  float* __restrict__ part) {
  const int bh = blockIdx.x >> 5;     // 0..7
  const int chunk = blockIdx.x & 31;  // 0..31
  const float* src = O + (size_t)bh * (HD * PP) + (size_t)chunk * 8192;
  float s1 = 0.f, s2 = 0.f;
  for (int i = threadIdx.x * 4; i < 8192; i += 1024) {
    const float4 v4 = *(const float4*)&src[i];
    s1 += v4.x + v4.y + v4.z + v4.w;
    s2 += v4.x * v4.x + v4.y * v4.y + v4.z * v4.z + v4.w * v4.w;
  }
  __shared__ float r1[4], r2[4];
  s1 = wave_sum(s1);
  s2 = wave_sum(s2);
  const int lane = threadIdx.x & 63, wid = threadIdx.x >> 6;
  if (lane == 0) {
    r1[wid] = s1;
    r2[wid] = s2;
  }
  __syncthreads();
  if (threadIdx.x == 0) {
    part[blockIdx.x * 2] = r1[0] + r1[1] + r1[2] + r1[3];
    part[blockIdx.x * 2 + 1] = r2[0] + r2[1] + r2[2] + r2[3];
  }
}

__global__ void k_gnstats2(const float* __restrict__ part,
                           float* __restrict__ stats) {
  const int t = threadIdx.x;  // 0..63 ; group = t>>3, sub = t&7
  const int g = t >> 3, sub = t & 7;
  float s1 = 0.f, s2 = 0.f;
  for (int c = sub * 4; c < (sub + 1) * 4; ++c) {
    s1 += part[(g * 32 + c) * 2];
    s2 += part[(g * 32 + c) * 2 + 1];
  }
#pragma unroll
  for (int off = 4; off > 0; off >>= 1) {
    s1 += __shfl_down(s1, off);
    s2 += __shfl_down(s2, off);
  }
  if (sub == 0) {
    const float inv = 1.0f / (HD * PP);
    const float mu = s1 * inv;
    const float var = s2 * inv - mu * mu;
    stats[g * 2] = mu;
    stats[g * 2 + 1] = rsqrtf(var + 1e-5f);
  }
}

extern "C" void kernel_launch(void* const* d_in, const int* in_sizes, int n_in,
                              void* d_out, int out_size, void* d_ws,
                              size_t ws_size, hipStream_t stream) {
  const float* x = (const float*)d_in[0];
  const float* Wq = (const float*)d_in[1];
  const float* Wk = (const float*)d_in[2];
  const float* Wv = (const float*)d_in[3];
  const float* Wo = (const float*)d_in[4];
  const float* bo = (const float*)d_in[5];
  const float* dirW = (const float*)d_in[6];
  const float* dirb = (const float*)d_in[7];
  const float* gnw = (const float*)d_in[8];
  const float* gnb = (const float*)d_in[9];
  float* outp = (float*)d_out;

  float* ws = (float*)d_ws;
  float* avg = ws;              // 512
  float* offs = ws + 512;       // 1024
  float* stats = ws + 1536;     // 16
  float* part = ws + 1600;      // 512
  float* Qb = ws + 4096;        // 2,097,152  f32 [b][c][p]
  float* Kb = Qb + 2097152;     // 2,097,152  f32 staging
  float* Vb = Kb + 2097152;     // 2,097,152  f32 staging
  u16t* Kc = (u16t*)(Vb + 2097152);      // 2,097,152 bf16 (=1,048,576 f32)
  u16t* Vc = (u16t*)(Vb + 2097152 + 1048576);  // 2,097,152 bf16
  float* lg = Kb;               // aliases Kb (dead after repack): 1,048,576
  float* Ob = Vb;               // aliases Vb (dead after repack): 2,097,152

  k_avg<<<dim3(512), dim3(256), 0, stream>>>(x, avg);
  k_dirs<<<dim3(1), dim3(64), 0, stream>>>(avg, dirW, dirb, offs);
  k_gemm<0><<<dim3(64, 4, 2), dim3(256), 0, stream>>>(
      Wq, x, Qb, nullptr, nullptr, nullptr, nullptr, nullptr);
  k_gemm<0><<<dim3(64, 4, 2), dim3(256), 0, stream>>>(
      Wk, x, Kb, nullptr, nullptr, nullptr, nullptr, nullptr);
  k_gemm<0><<<dim3(64, 4, 2), dim3(256), 0, stream>>>(
      Wv, x, Vb, nullptr, nullptr, nullptr, nullptr, nullptr);
  k_repack<<<dim3(16, 8, 8), dim3(256), 0, stream>>>(Kb, Kc);
  k_repack<<<dim3(16, 8, 8), dim3(256), 0, stream>>>(Vb, Vc);
  k_logits<<<dim3(16, 4, 8), dim3(256), 0, stream>>>(Qb, (const uint4*)Kc,
                                                     offs, lg);
  k_pv<<<dim3(16, 4, 8), dim3(256), 0, stream>>>((const uint4*)Vc, lg, offs,
                                                 Ob);
  k_gnstats1<<<dim3(256), dim3(256), 0, stream>>>(Ob, part);
  k_gnstats2<<<dim3(1), dim3(64), 0, stream>>>(part, stats);
  k_gemm<1><<<dim3(64, 4, 2), dim3(256), 0, stream>>>(Wo, Ob, outp, stats, gnw,
                                                      gnb, bo, x);
}

// Round 4
// 102.531 us; speedup vs baseline: 4.2771x; 1.4904x over previous
//
#include <hip/hip_runtime.h>
#include <math.h>

#define PP 4096
#define CDIM 256
#define NHEADS 4
#define HD 64

typedef unsigned int u32t;
typedef unsigned short u16t;
typedef __attribute__((ext_vector_type(8))) short bf16x8;
typedef __attribute__((ext_vector_type(4))) float f32x4;

__device__ __forceinline__ float wave_sum(float v) {
#pragma unroll
  for (int off = 32; off > 0; off >>= 1) v += __shfl_down(v, off);
  return v;
}

__device__ __forceinline__ float bflo(u32t w) {
  return __uint_as_float(w << 16);
}
__device__ __forceinline__ float bfhi(u32t w) {
  return __uint_as_float(w & 0xffff0000u);
}
__device__ __forceinline__ u16t f2bf(float f) {
  u32t u = __float_as_uint(f);
  u = u + 0x7fffu + ((u >> 16) & 1u);
  return (u16t)(u >> 16);
}
__device__ __forceinline__ u32t pack2(float lo, float hi) {
  const u32t a = __float_as_uint(lo), b = __float_as_uint(hi);
  const u32t l = (a + 0x7fffu + ((a >> 16) & 1u)) >> 16;
  const u32t h = (b + 0x7fffu + ((b >> 16) & 1u)) & 0xffff0000u;
  return l | h;
}

// ---------------- avg pool over H,W ----------------
__global__ __launch_bounds__(256) void k_avg(const float* __restrict__ x,
                                             float* __restrict__ avg) {
  const int bc = blockIdx.x;  // b*256 + c
  const float* src = x + (size_t)bc * PP;
  float s = 0.f;
  for (int i = threadIdx.x; i < PP; i += 256) s += src[i];
  __shared__ float red[4];
  s = wave_sum(s);
  const int lane = threadIdx.x & 63, wid = threadIdx.x >> 6;
  if (lane == 0) red[wid] = s;
  __syncthreads();
  if (threadIdx.x == 0)
    avg[bc] = (red[0] + red[1] + red[2] + red[3]) * (1.0f / PP);
}

// ---------------- dirs + per-(b,h,s,m) normalized offsets ----------------
__global__ void k_dirs(const float* __restrict__ avg, const float* __restrict__ dirW,
                       const float* __restrict__ dirb, float* __restrict__ offs) {
  const int r = threadIdx.x;  // 64 threads: b = r>>5, row = r&31
  __shared__ float dv[2][32];
  {
    const int b = r >> 5, row = r & 31;
    const float* a = avg + b * CDIM;
    const float* w = dirW + row * CDIM;
    float s = dirb[row];
    for (int c = 0; c < CDIM; ++c) s = fmaf(a[c], w[c], s);
    dv[b][row] = s;
  }
  __syncthreads();
  if (r < 32) {  // one (b,h,s) each: b = r>>4, hs = r&15
    const int b = r >> 4, hs = r & 15;
    float vx = dv[b][hs * 2], vy = dv[b][hs * 2 + 1];
    const float n = fmaxf(sqrtf(vx * vx + vy * vy), 1e-6f);
    vx /= n;
    vy /= n;
#pragma unroll
    for (int m = 0; m < 8; ++m) {
      const float t = -0.5f + m * (1.0f / 7.0f);  // linspace(-0.5,0.5,8)
      const int o = ((b * 16 + hs) * 8 + m) * 2;
      offs[o] = vx * t;
      offs[o + 1] = vy * t;
    }
  }
}

// ---- pack x f32 [b][c][p] -> bf16 chunked [b][c32][p][8] ----
__global__ __launch_bounds__(256) void k_pack_x(const float* __restrict__ src,
                                                u16t* __restrict__ dst) {
  const int p = blockIdx.x * 256 + threadIdx.x;
  const int c32 = blockIdx.y;  // 0..31
  const int b = blockIdx.z;
  const float* s = src + ((size_t)b * CDIM + c32 * 8) * PP + p;
  u32t u[4];
#pragma unroll
  for (int jw = 0; jw < 4; ++jw)
    u[jw] = pack2(s[(size_t)(2 * jw) * PP], s[(size_t)(2 * jw + 1) * PP]);
  *(uint4*)&dst[(((size_t)b * 32 + c32) * PP + p) * 8] = *(const uint4*)u;
}

// ---- pack Wq/Wk/Wv f32 [o][c] -> bf16 A-layout [m][c32][o][8] ----
__global__ __launch_bounds__(256) void k_pack_w(const float* __restrict__ Wq,
                                                const float* __restrict__ Wk,
                                                const float* __restrict__ Wv,
                                                u16t* __restrict__ Wa) {
  const int c32 = blockIdx.x;  // 0..31
  const int m = blockIdx.y;    // 0..2
  const int o = threadIdx.x;   // 0..255
  const float* W = (m == 0 ? Wq : (m == 1 ? Wk : Wv));
  const float4 a = *(const float4*)&W[o * CDIM + c32 * 8];
  const float4 bq = *(const float4*)&W[o * CDIM + c32 * 8 + 4];
  u32t u[4];
  u[0] = pack2(a.x, a.y);
  u[1] = pack2(a.z, a.w);
  u[2] = pack2(bq.x, bq.y);
  u[3] = pack2(bq.z, bq.w);
  *(uint4*)&Wa[(((size_t)m * 32 + c32) * CDIM + o) * 8] = *(const uint4*)u;
}

// ---- pack Wo scaled by GN scale: Woa[b][c32][o][8] bf16 ----
__global__ __launch_bounds__(256) void k_pack_wo(const float* __restrict__ Wo,
                                                 const float* __restrict__ stats,
                                                 const float* __restrict__ gnw,
                                                 u16t* __restrict__ Woa) {
  const int c32 = blockIdx.x;  // 0..31
  const int b = blockIdx.y;    // 0..1
  const int o = threadIdx.x;
  const int g = c32 >> 3;
  const float rs = stats[(b * NHEADS + g) * 2 + 1];
  float w[8];
#pragma unroll
  for (int j = 0; j < 8; ++j) {
    const int c = c32 * 8 + j;
    w[j] = Wo[o * CDIM + c] * rs * gnw[c];
  }
  u32t u[4];
#pragma unroll
  for (int jw = 0; jw < 4; ++jw) u[jw] = pack2(w[2 * jw], w[2 * jw + 1]);
  *(uint4*)&Woa[(((size_t)b * 32 + c32) * CDIM + o) * 8] = *(const uint4*)u;
}

// ---- per-(b,o) bias: bo + sum_c Wo[o][c]*(gnb[c]-mu*rs*gnw[c]) ----
__global__ __launch_bounds__(256) void k_obias(const float* __restrict__ Wo,
                                               const float* __restrict__ bo,
                                               const float* __restrict__ stats,
                                               const float* __restrict__ gnw,
                                               const float* __restrict__ gnb,
                                               float* __restrict__ obias) {
  const int b = blockIdx.x;
  const int o = threadIdx.x;
  float acc = bo[o];
  for (int c = 0; c < CDIM; ++c) {
    const int g = c >> 6;
    const float mu = stats[(b * NHEADS + g) * 2];
    const float rs = stats[(b * NHEADS + g) * 2 + 1];
    acc = fmaf(Wo[o * CDIM + c], gnb[c] - mu * rs * gnw[c], acc);
  }
  obias[b * CDIM + o] = acc;
}

// ---- fused QKV MFMA GEMM: out m in {Q,K,V}, bf16 chunked outputs ----
__global__ __launch_bounds__(256) void k_mfma_qkv(const u16t* __restrict__ Wa,
                                                  const u16t* __restrict__ xb,
                                                  u16t* __restrict__ Qc,
                                                  u16t* __restrict__ Kc,
                                                  u16t* __restrict__ Vc) {
  const int p0 = blockIdx.x * 64;
  const int ot = blockIdx.y;      // 0..11
  const int m = ot >> 2;          // matrix: 0=Q,1=K,2=V
  const int ob = (ot & 3) * 64;   // o base within matrix
  const int b = blockIdx.z;
  const int l = threadIdx.x & 63, w = threadIdx.x >> 6;
  const int lm = l & 15, lk = l >> 4;
  f32x4 acc[4] = {};
  const u16t* Ab = Wa + ((size_t)m * 32) * CDIM * 8 + (ob + w * 16 + lm) * 8;
  const u16t* Bb = xb + ((size_t)b * 32) * PP * 8 + ((size_t)p0 + lm) * 8;
  for (int c0 = 0; c0 < CDIM; c0 += 32) {
    const int ch = (c0 >> 3) + lk;
    const bf16x8 af = *(const bf16x8*)(Ab + (size_t)ch * CDIM * 8);
#pragma unroll
    for (int j = 0; j < 4; ++j) {
      const bf16x8 bf = *(const bf16x8*)(Bb + ((size_t)ch * PP + j * 16) * 8);
      acc[j] = __builtin_amdgcn_mfma_f32_16x16x32_bf16(af, bf, acc[j], 0, 0, 0);
    }
  }
  u16t* dst = (m == 0 ? Qc : (m == 1 ? Kc : Vc));
#pragma unroll
  for (int j = 0; j < 4; ++j) {
    const int p = p0 + j * 16 + lm;
#pragma unroll
    for (int r = 0; r < 4; ++r) {
      const int o = ob + w * 16 + lk * 4 + r;
      dst[(((size_t)b * 32 + (o >> 3)) * PP + p) * 8 + (o & 7)] =
          f2bf(acc[j][r]);
    }
  }
}

// ---- final MFMA GEMM: out = Wo' @ Obc + obias + x ----
__global__ __launch_bounds__(256) void k_mfma_out(const u16t* __restrict__ Woa,
                                                  const u16t* __restrict__ Obc,
                                                  const float* __restrict__ obias,
                                                  const float* __restrict__ x,
                                                  float* __restrict__ outp) {
  const int p0 = blockIdx.x * 64;
  const int ob = blockIdx.y * 64;
  const int b = blockIdx.z;
  const int l = threadIdx.x & 63, w = threadIdx.x >> 6;
  const int lm = l & 15, lk = l >> 4;
  f32x4 acc[4] = {};
  const u16t* Ab = Woa + ((size_t)b * 32) * CDIM * 8 + (ob + w * 16 + lm) * 8;
  const u16t* Bb = Obc + ((size_t)b * 32) * PP * 8 + ((size_t)p0 + lm) * 8;
  for (int c0 = 0; c0 < CDIM; c0 += 32) {
    const int ch = (c0 >> 3) + lk;
    const bf16x8 af = *(const bf16x8*)(Ab + (size_t)ch * CDIM * 8);
#pragma unroll
    for (int j = 0; j < 4; ++j) {
      const bf16x8 bf = *(const bf16x8*)(Bb + ((size_t)ch * PP + j * 16) * 8);
      acc[j] = __builtin_amdgcn_mfma_f32_16x16x32_bf16(af, bf, acc[j], 0, 0, 0);
    }
  }
#pragma unroll
  for (int j = 0; j < 4; ++j) {
    const int p = p0 + j * 16 + lm;
#pragma unroll
    for (int r = 0; r < 4; ++r) {
      const int o = ob + w * 16 + lk * 4 + r;
      const size_t idx = ((size_t)b * CDIM + o) * PP + p;
      outp[idx] = acc[j][r] + obias[b * CDIM + o] + x[idx];
    }
  }
}

// ---------------- bilinear sample setup (shift constant per b,h,s,m) ------
struct Samp {
  int i00, i01, i10, i11;
  float w00, w01, w10, w11;
};
__device__ __forceinline__ Samp samp(int xi, int yi, float dxn, float dyn) {
  float gx = fminf(fmaxf(-1.0f + xi * (2.0f / 63.0f) + dxn, -1.0f), 1.0f);
  float gy = fminf(fmaxf(-1.0f + yi * (2.0f / 63.0f) + dyn, -1.0f), 1.0f);
  const float px = (gx + 1.0f) * 31.5f;
  const float py = (gy + 1.0f) * 31.5f;
  const float x0f = floorf(px), y0f = floorf(py);
  const float fx = px - x0f, fy = py - y0f;
  int x0 = (int)x0f;
  x0 = x0 < 0 ? 0 : (x0 > 63 ? 63 : x0);
  int y0 = (int)y0f;
  y0 = y0 < 0 ? 0 : (y0 > 63 ? 63 : y0);
  const int x1 = x0 + 1 > 63 ? 63 : x0 + 1;
  const int y1 = y0 + 1 > 63 ? 63 : y0 + 1;
  Samp sp;
  sp.i00 = y0 * 64 + x0;
  sp.i01 = y0 * 64 + x1;
  sp.i10 = y1 * 64 + x0;
  sp.i11 = y1 * 64 + x1;
  const float ifx = 1.0f - fx, ify = 1.0f - fy;
  sp.w00 = ifx * ify;
  sp.w01 = fx * ify;
  sp.w10 = ifx * fy;
  sp.w11 = fx * fy;
  return sp;
}

__device__ __forceinline__ float dot8(const float* q, uint4 v) {
  float a = q[0] * bflo(v.x);
  a = fmaf(q[1], bfhi(v.x), a);
  a = fmaf(q[2], bflo(v.y), a);
  a = fmaf(q[3], bfhi(v.y), a);
  a = fmaf(q[4], bflo(v.z), a);
  a = fmaf(q[5], bfhi(v.z), a);
  a = fmaf(q[6], bflo(v.w), a);
  a = fmaf(q[7], bfhi(v.w), a);
  return a;
}

// ---------------- logits: thread per (p, strip) over 8 m ----------------
__global__ __launch_bounds__(256) void k_logits(const uint4* __restrict__ Qc,
                                                const uint4* __restrict__ Kc,
                                                const float* __restrict__ offs,
                                                float* __restrict__ lg) {
  const int p = blockIdx.x * 256 + threadIdx.x;
  const int s = blockIdx.y;   // strip 0..3
  const int bh = blockIdx.z;  // 0..7
  const int b = bh >> 2, h = bh & 3;
  float q[64];
  {
    const uint4* Qp = Qc + ((size_t)b * 32 + h * 8) * PP + p;
#pragma unroll
    for (int c8 = 0; c8 < 8; ++c8) {
      const uint4 v = Qp[(size_t)c8 * PP];
      q[c8 * 8 + 0] = bflo(v.x);
      q[c8 * 8 + 1] = bfhi(v.x);
      q[c8 * 8 + 2] = bflo(v.y);
      q[c8 * 8 + 3] = bfhi(v.y);
      q[c8 * 8 + 4] = bflo(v.z);
      q[c8 * 8 + 5] = bfhi(v.z);
      q[c8 * 8 + 6] = bflo(v.w);
      q[c8 * 8 + 7] = bfhi(v.w);
    }
  }
  const int xi = p & 63, yi = p >> 6;
  for (int m = 0; m < 8; ++m) {
    const int obase = ((b * 16 + h * 4 + s) * 8 + m) * 2;
    const Samp sp = samp(xi, yi, offs[obase], offs[obase + 1]);
    float a00 = 0.f, a01 = 0.f, a10 = 0.f, a11 = 0.f;
#pragma unroll
    for (int c8 = 0; c8 < 8; ++c8) {
      const uint4* Kb8 = Kc + ((size_t)b * 32 + h * 8 + c8) * PP;
      const uint4 v00 = Kb8[sp.i00];
      const uint4 v01 = Kb8[sp.i01];
      const uint4 v10 = Kb8[sp.i10];
      const uint4 v11 = Kb8[sp.i11];
      const float* qq = q + c8 * 8;
      a00 += dot8(qq, v00);
      a01 += dot8(qq, v01);
      a10 += dot8(qq, v10);
      a11 += dot8(qq, v11);
    }
    const float lgv =
        (sp.w00 * a00 + sp.w01 * a01 + sp.w10 * a10 + sp.w11 * a11) * 0.125f;
    lg[((size_t)bh * 32 + s * 8 + m) * PP + p] = lgv;
  }
}

__device__ __forceinline__ void acc8(float* a, uint4 v, float w) {
  a[0] = fmaf(w, bflo(v.x), a[0]);
  a[1] = fmaf(w, bfhi(v.x), a[1]);
  a[2] = fmaf(w, bflo(v.y), a[2]);
  a[3] = fmaf(w, bfhi(v.y), a[3]);
  a[4] = fmaf(w, bflo(v.z), a[4]);
  a[5] = fmaf(w, bfhi(v.z), a[5]);
  a[6] = fmaf(w, bflo(v.w), a[6]);
  a[7] = fmaf(w, bfhi(v.w), a[7]);
}

// ---- PV with fused softmax; writes bf16 chunked Obc ----
__global__ __launch_bounds__(256) void k_pv(const uint4* __restrict__ Vc,
                                            const float* __restrict__ lg,
                                            const float* __restrict__ offs,
                                            u16t* __restrict__ Obc) {
  const int p = blockIdx.x * 256 + threadIdx.x;
  const int g = blockIdx.y;   // 0..3 -> d range g*16..g*16+15
  const int bh = blockIdx.z;  // 0..7
  const int b = bh >> 2, h = bh & 3;
  const float* ap = lg + (size_t)bh * 32 * PP + p;
  float mx = -1e30f;
#pragma unroll
  for (int k = 0; k < 32; ++k) mx = fmaxf(mx, ap[(size_t)k * PP]);
  float sum = 0.f;
#pragma unroll
  for (int k = 0; k < 32; ++k) sum += __expf(ap[(size_t)k * PP] - mx);
  const float inv = 1.0f / sum;
  const int xi = p & 63, yi = p >> 6;
  float acc[16] = {};
  for (int k = 0; k < 32; ++k) {
    const int obase = ((b * 16 + h * 4 + (k >> 3)) * 8 + (k & 7)) * 2;
    const Samp sp = samp(xi, yi, offs[obase], offs[obase + 1]);
    const float ww = __expf(ap[(size_t)k * PP] - mx) * inv;
    const float w00 = ww * sp.w00, w01 = ww * sp.w01;
    const float w10 = ww * sp.w10, w11 = ww * sp.w11;
#pragma unroll
    for (int cc = 0; cc < 2; ++cc) {
      const uint4* Vb8 = Vc + ((size_t)b * 32 + h * 8 + 2 * g + cc) * PP;
      const uint4 v00 = Vb8[sp.i00];
      const uint4 v01 = Vb8[sp.i01];
      const uint4 v10 = Vb8[sp.i10];
      const uint4 v11 = Vb8[sp.i11];
      float* a = acc + cc * 8;
      acc8(a, v00, w00);
      acc8(a, v01, w01);
      acc8(a, v10, w10);
      acc8(a, v11, w11);
    }
  }
#pragma unroll
  for (int cc = 0; cc < 2; ++cc) {
    const int c32 = h * 8 + g * 2 + cc;
    u32t u[4];
#pragma unroll
    for (int jw = 0; jw < 4; ++jw)
      u[jw] = pack2(acc[cc * 8 + 2 * jw], acc[cc * 8 + 2 * jw + 1]);
    *(uint4*)&Obc[(((size_t)b * 32 + c32) * PP + p) * 8] = *(const uint4*)u;
  }
}

// ---------------- GroupNorm stats, two-stage (bf16 input) ----------------
__global__ __launch_bounds__(256) void k_gnstats1(const u16t* __restrict__ Obc,
                                                  float* __restrict__ part) {
  const int bh = blockIdx.x >> 5;     // 0..7
  const int chunk = blockIdx.x & 31;  // 0..31
  const u16t* src = Obc + (size_t)bh * 262144 + (size_t)chunk * 8192;
  float s1 = 0.f, s2 = 0.f;
  for (int i = threadIdx.x * 8; i < 8192; i += 2048) {
    const uint4 v = *(const uint4*)&src[i];
    const float f0 = bflo(v.x), f1 = bfhi(v.x), f2 = bflo(v.y), f3 = bfhi(v.y);
    const float f4 = bflo(v.z), f5 = bfhi(v.z), f6 = bflo(v.w), f7 = bfhi(v.w);
    s1 += (f0 + f1) + (f2 + f3) + (f4 + f5) + (f6 + f7);
    s2 += f0 * f0 + f1 * f1 + f2 * f2 + f3 * f3 + f4 * f4 + f5 * f5 +
          f6 * f6 + f7 * f7;
  }
  __shared__ float r1[4], r2[4];
  s1 = wave_sum(s1);
  s2 = wave_sum(s2);
  const int lane = threadIdx.x & 63, wid = threadIdx.x >> 6;
  if (lane == 0) {
    r1[wid] = s1;
    r2[wid] = s2;
  }
  __syncthreads();
  if (threadIdx.x == 0) {
    part[blockIdx.x * 2] = r1[0] + r1[1] + r1[2] + r1[3];
    part[blockIdx.x * 2 + 1] = r2[0] + r2[1] + r2[2] + r2[3];
  }
}

__global__ void k_gnstats2(const float* __restrict__ part,
                           float* __restrict__ stats) {
  const int t = threadIdx.x;  // 0..63 ; group = t>>3, sub = t&7
  const int g = t >> 3, sub = t & 7;
  float s1 = 0.f, s2 = 0.f;
  for (int c = sub * 4; c < (sub + 1) * 4; ++c) {
    s1 += part[(g * 32 + c) * 2];
    s2 += part[(g * 32 + c) * 2 + 1];
  }
#pragma unroll
  for (int off = 4; off > 0; off >>= 1) {
    s1 += __shfl_down(s1, off);
    s2 += __shfl_down(s2, off);
  }
  if (sub == 0) {
    const float inv = 1.0f / (HD * PP);
    const float mu = s1 * inv;
    const float var = s2 * inv - mu * mu;
    stats[g * 2] = mu;
    stats[g * 2 + 1] = rsqrtf(var + 1e-5f);
  }
}

extern "C" void kernel_launch(void* const* d_in, const int* in_sizes, int n_in,
                              void* d_out, int out_size, void* d_ws,
                              size_t ws_size, hipStream_t stream) {
  const float* x = (const float*)d_in[0];
  const float* Wq = (const float*)d_in[1];
  const float* Wk = (const float*)d_in[2];
  const float* Wv = (const float*)d_in[3];
  const float* Wo = (const float*)d_in[4];
  const float* bo = (const float*)d_in[5];
  const float* dirW = (const float*)d_in[6];
  const float* dirb = (const float*)d_in[7];
  const float* gnw = (const float*)d_in[8];
  const float* gnb = (const float*)d_in[9];
  float* outp = (float*)d_out;

  float* ws = (float*)d_ws;
  float* avg = ws;            // 512
  float* offs = ws + 512;     // 1024 -> ends 1536
  float* stats = ws + 1536;   // 16
  float* part = ws + 1600;    // 512 -> ends 2112
  float* obias = ws + 2176;   // 512 -> ends 2688
  u16t* xb = (u16t*)(ws + 4096);      // 2,097,152 u16 (1,048,576 f32)
  u16t* Wa = (u16t*)(ws + 1052672);   // 196,608 u16 (98,304 f32)
  u16t* Woa = (u16t*)(ws + 1150976);  // 131,072 u16 (65,536 f32)
  u16t* Qc = (u16t*)(ws + 1216512);   // 2,097,152 u16
  u16t* Kc = (u16t*)(ws + 2265088);   // 2,097,152 u16
  u16t* Vc = (u16t*)(ws + 3313664);   // 2,097,152 u16
  float* lg = ws + 4362240;           // 1,048,576 f32
  u16t* Obc = (u16t*)(ws + 5410816);  // 2,097,152 u16  (ends 6,459,392 f32)

  k_avg<<<dim3(512), dim3(256), 0, stream>>>(x, avg);
  k_dirs<<<dim3(1), dim3(64), 0, stream>>>(avg, dirW, dirb, offs);
  k_pack_x<<<dim3(16, 32, 2), dim3(256), 0, stream>>>(x, xb);
  k_pack_w<<<dim3(32, 3), dim3(256), 0, stream>>>(Wq, Wk, Wv, Wa);
  k_mfma_qkv<<<dim3(64, 12, 2), dim3(256), 0, stream>>>(Wa, xb, Qc, Kc, Vc);
  k_logits<<<dim3(16, 4, 8), dim3(256), 0, stream>>>(
      (const uint4*)Qc, (const uint4*)Kc, offs, lg);
  k_pv<<<dim3(16, 4, 8), dim3(256), 0, stream>>>((const uint4*)Vc, lg, offs,
                                                 Obc);
  k_gnstats1<<<dim3(256), dim3(256), 0, stream>>>(Obc, part);
  k_gnstats2<<<dim3(1), dim3(64), 0, stream>>>(part, stats);
  k_pack_wo<<<dim3(32, 2), dim3(256), 0, stream>>>(Wo, stats, gnw, Woa);
  k_obias<<<dim3(2), dim3(256), 0, stream>>>(Wo, bo, stats, gnw, gnb, obias);
  k_mfma_out<<<dim3(64, 4, 2), dim3(256), 0, stream>>>(Woa, Obc, obias, x,
                                                       outp);
}